// Round 2
// baseline (177.268 us; speedup 1.0000x reference)
//
#include <hip/hip_runtime.h>

// Problem geometry (fixed by the reference).
#define OUT_FEATURES 8192
#define PACKED_COLS  4096          // IN_FEATURES / 2, one packed byte per int32
#define PCOLS_SHIFT  12            // log2(PACKED_COLS)

typedef int   __attribute__((ext_vector_type(4))) int4v;
typedef float __attribute__((ext_vector_type(4))) float4v;

// Each thread: load 8 packed ints (2x 16B nontemporal), emit 16 floats
// (4x float4 nontemporal stores = 64B contiguous).
__global__ void __launch_bounds__(256)
dequant_u4_kernel(const int* __restrict__ w,
                  const float* __restrict__ scale,
                  const float* __restrict__ zero_point,
                  float* __restrict__ out) {
    const int tid = blockIdx.x * blockDim.x + threadIdx.x;   // 0 .. 8192*4096/8 - 1
    const int packed_idx = tid << 3;                         // first packed col handled
    const int row = packed_idx >> PCOLS_SHIFT;
    const int col = packed_idx & (PACKED_COLS - 1);

    // Issue both 16B loads before any use (memory ILP).
    const int4v wv0 = __builtin_nontemporal_load(
        reinterpret_cast<const int4v*>(w + packed_idx));
    const int4v wv1 = __builtin_nontemporal_load(
        reinterpret_cast<const int4v*>(w + packed_idx + 4));

    const float s = scale[row];
    const float b = -zero_point[row] * s;                    // out = n*s + b

    float* op = out + (size_t)row * (2 * PACKED_COLS) + 2 * col;

    float4v o;
    o.x = fmaf((float)( wv0.x        & 0xF), s, b);
    o.y = fmaf((float)((wv0.x >> 4) & 0xF), s, b);
    o.z = fmaf((float)( wv0.y        & 0xF), s, b);
    o.w = fmaf((float)((wv0.y >> 4) & 0xF), s, b);
    __builtin_nontemporal_store(o, reinterpret_cast<float4v*>(op));

    o.x = fmaf((float)( wv0.z        & 0xF), s, b);
    o.y = fmaf((float)((wv0.z >> 4) & 0xF), s, b);
    o.z = fmaf((float)( wv0.w        & 0xF), s, b);
    o.w = fmaf((float)((wv0.w >> 4) & 0xF), s, b);
    __builtin_nontemporal_store(o, reinterpret_cast<float4v*>(op + 4));

    o.x = fmaf((float)( wv1.x        & 0xF), s, b);
    o.y = fmaf((float)((wv1.x >> 4) & 0xF), s, b);
    o.z = fmaf((float)( wv1.y        & 0xF), s, b);
    o.w = fmaf((float)((wv1.y >> 4) & 0xF), s, b);
    __builtin_nontemporal_store(o, reinterpret_cast<float4v*>(op + 8));

    o.x = fmaf((float)( wv1.z        & 0xF), s, b);
    o.y = fmaf((float)((wv1.z >> 4) & 0xF), s, b);
    o.z = fmaf((float)( wv1.w        & 0xF), s, b);
    o.w = fmaf((float)((wv1.w >> 4) & 0xF), s, b);
    __builtin_nontemporal_store(o, reinterpret_cast<float4v*>(op + 12));
}

extern "C" void kernel_launch(void* const* d_in, const int* in_sizes, int n_in,
                              void* d_out, int out_size, void* d_ws, size_t ws_size,
                              hipStream_t stream) {
    const int*   w          = (const int*)d_in[0];
    const float* scale      = (const float*)d_in[1];
    const float* zero_point = (const float*)d_in[2];
    float*       out        = (float*)d_out;

    const int total_threads = OUT_FEATURES * PACKED_COLS / 8;  // 4,194,304
    const int block = 256;
    const int grid  = total_threads / block;                   // 16384, exact

    dequant_u4_kernel<<<grid, block, 0, stream>>>(w, scale, zero_point, out);
}

// Round 4
// 61.396 us; speedup vs baseline: 2.8873x; 2.8873x over previous
//
#include <hip/hip_runtime.h>

// Problem geometry (fixed by the reference).
#define OUT_FEATURES 8192
#define PACKED_COLS  4096   // int32 elements per row; each int32 holds ONE packed byte
// Thread t: loads int2 {w[2t], w[2t+1]} (8B/lane, 512B/wave dense),
// writes float4 at out[4t] (16B/lane, 1024B/wave dense) nontemporally.
// Dense per-instruction footprints -> nt stores emit only full 128B lines
// (R2 showed nt + partial-line strided stores = 1.58x write amplification).

typedef float __attribute__((ext_vector_type(4))) float4v;

__global__ void __launch_bounds__(256)
dequant_u4_kernel(const int* __restrict__ w,
                  const float* __restrict__ scale,
                  const float* __restrict__ zero_point,
                  float* __restrict__ out) {
    const int t = blockIdx.x * blockDim.x + threadIdx.x;  // 0 .. 16,777,215

    const int2 wv = *reinterpret_cast<const int2*>(w + 2 * t);

    const int row = t >> 11;              // 2048 threads per output row
    const float s = scale[row];
    const float b = -zero_point[row] * s; // out = n*s + b

    float4v o;
    o.x = fmaf((float)( wv.x       & 0xF), s, b);
    o.y = fmaf((float)((wv.x >> 4) & 0xF), s, b);
    o.z = fmaf((float)( wv.y       & 0xF), s, b);
    o.w = fmaf((float)((wv.y >> 4) & 0xF), s, b);

    __builtin_nontemporal_store(o, reinterpret_cast<float4v*>(out) + t);
}

extern "C" void kernel_launch(void* const* d_in, const int* in_sizes, int n_in,
                              void* d_out, int out_size, void* d_ws, size_t ws_size,
                              hipStream_t stream) {
    const int*   w          = (const int*)d_in[0];
    const float* scale      = (const float*)d_in[1];
    const float* zero_point = (const float*)d_in[2];
    float*       out        = (float*)d_out;

    const int total_threads = OUT_FEATURES * PACKED_COLS / 2;  // 16,777,216
    const int block = 256;
    const int grid  = total_threads / block;                   // 65536, exact

    dequant_u4_kernel<<<grid, block, 0, stream>>>(w, scale, zero_point, out);
}